// Round 8
// baseline (191.872 us; speedup 1.0000x reference)
//
#include <hip/hip_runtime.h>

#define NEXP 8
#define NPB 1024        // probs blocks (8 tokens each)
#define NFL 1788        // fill blocks
#define NRK 256         // rank blocks (32 pairs x 8 subs)
#define MAXCAP 384
#define NTHR 512

typedef unsigned long long u64;
typedef unsigned int u32;

// flags layout (ints): [0..3] pflag per group, [4..7] rkflag per group, [8] fflag
union __align__(16) Smem {
    struct { float wl[NEXP * 1024]; double zred[8]; } a;                // probs: 32.1 KB
    struct { u64 keys[2048]; int part[NTHR]; } b;                       // rank: 18 KB
    struct { int avail[2048]; int cnt[32]; int cnt2[32];
             u64 cbuf[NEXP * MAXCAP]; } c;                              // assign: 32.5 KB
};

__global__ __launch_bounds__(NTHR) void moe_fat_kernel(
    const float* __restrict__ x,      // [GT, 1024]
    const float* __restrict__ w,      // [8, 1024]
    const float* __restrict__ bias,   // [8]
    float* __restrict__ out,
    float* __restrict__ probsT,       // [E][GT]
    u64* __restrict__ skey,           // [E*G][T]
    double* __restrict__ zpart,       // [NPB]
    int* __restrict__ flags,          // zeroed by memset node
    long long nout4, int out_size,
    long long GT, int T, int G, int cap)
{
    __shared__ Smem sm;
    const int b = blockIdx.x;
    const int tid = threadIdx.x;
    const int lane = tid & 63;
    const int wv = tid >> 6;

    if (b < NPB) {
        // ================= probs: 8 tokens (1 per wave) =================
        for (int i = tid; i < NEXP * 1024 / 4; i += NTHR)
            reinterpret_cast<float4*>(sm.a.wl)[i] = reinterpret_cast<const float4*>(w)[i];
        __syncthreads();

        const long long t = (long long)b * 8 + wv;
        const float* xr = x + t * 1024;
        float acc[NEXP];
#pragma unroll
        for (int e = 0; e < NEXP; ++e) acc[e] = 0.f;
#pragma unroll
        for (int c = 0; c < 4; ++c) {
            const int d = c * 256 + lane * 4;
            const float4 xv = *reinterpret_cast<const float4*>(xr + d);
#pragma unroll
            for (int e = 0; e < NEXP; ++e) {
                const float4 wv4 = *reinterpret_cast<const float4*>(sm.a.wl + e * 1024 + d);
                acc[e] = fmaf(xv.x, wv4.x, acc[e]);
                acc[e] = fmaf(xv.y, wv4.y, acc[e]);
                acc[e] = fmaf(xv.z, wv4.z, acc[e]);
                acc[e] = fmaf(xv.w, wv4.w, acc[e]);
            }
        }
#pragma unroll
        for (int e = 0; e < NEXP; ++e) {
#pragma unroll
            for (int off = 32; off; off >>= 1) acc[e] += __shfl_xor(acc[e], off, 64);
        }
        if (lane == 0) {
            double l[NEXP]; double mx = -1e300;
#pragma unroll
            for (int e = 0; e < NEXP; ++e) { l[e] = (double)acc[e] + (double)bias[e]; mx = fmax(mx, l[e]); }
            double ex[NEXP]; double s = 0.0;
#pragma unroll
            for (int e = 0; e < NEXP; ++e) { ex[e] = exp(l[e] - mx); s += ex[e]; }
            const double inv = 1.0 / s;
#pragma unroll
            for (int e = 0; e < NEXP; ++e) probsT[(long long)e * GT + t] = (float)(ex[e] * inv);
            const double lse = mx + log(s);
            sm.a.zred[wv] = lse * lse;
        }
        __syncthreads();
        if (tid == 0) {
            double s = 0.0;
#pragma unroll
            for (int i = 0; i < 8; ++i) s += sm.a.zred[i];
            zpart[b] = s;
            __threadfence();
            atomicAdd(&flags[b / (NPB / 4)], 1);     // pflag[g], g = b/256
        }
        return;
    }

    if (b < NPB + NFL) {
        // ================= zero-fill slice of d_out =================
        const int fb = b - NPB;
        const long long stride = (long long)NFL * NTHR;
        const float4 z = make_float4(0.f, 0.f, 0.f, 0.f);
        for (long long k = (long long)fb * NTHR + tid; k < nout4; k += stride)
            reinterpret_cast<float4*>(out)[k] = z;
        __syncthreads();
        if (tid == 0) { __threadfence(); atomicAdd(&flags[8], 1); }
        return;
    }

    if (b < NPB + NFL + NRK) {
        // ================= ranksort: pair = e*G+g, sub-slice of 256 tokens ======
        const int b3 = b - NPB - NFL;
        const int pair = b3 >> 3;
        const int sub  = b3 & 7;
        const int e = pair / G;
        const int g = pair - e * G;
        const int ptgt = NPB / G;                    // probs blocks per group
        if (tid == 0) {
            while (__hip_atomic_load(&flags[g], __ATOMIC_RELAXED, __HIP_MEMORY_SCOPE_AGENT) < ptgt)
                __builtin_amdgcn_s_sleep(2);
            __threadfence();                         // acquire: probsT visible
        }
        __syncthreads();

        const float* p = probsT + (long long)e * GT + (long long)g * T;
        for (int j = tid; j < 2048; j += NTHR)
            sm.b.keys[j] = ((u64)__float_as_uint(p[j]) << 32) | (u32)(~(u32)j);
        __syncthreads();
        const int slot = tid & 255;
        const int q = tid >> 8;                      // key-range half 0..1
        const u64 kt = sm.b.keys[sub * 256 + slot];
        const ulonglong2* k2 = reinterpret_cast<const ulonglong2*>(sm.b.keys) + q * 512;
        int r = 0;
#pragma unroll 8
        for (int j = 0; j < 512; ++j) {
            const ulonglong2 v = k2[j];
            r += (v.x > kt); r += (v.y > kt);
        }
        sm.b.part[tid] = r;
        __syncthreads();
        if (tid < 256) {
            const int rank = sm.b.part[tid] + sm.b.part[tid + 256];
            skey[(long long)pair * T + rank] = sm.b.keys[sub * 256 + tid];
        }
        __syncthreads();
        if (tid == 0) { __threadfence(); atomicAdd(&flags[4 + g], 1); }
        return;
    }

    // ================= assign block for group g =================
    const int g = b - NPB - NFL - NRK;
    const int rtgt = NRK / 4;                        // rank blocks per group (G=4)
    if (tid == 0) {
        while (__hip_atomic_load(&flags[4 + g], __ATOMIC_RELAXED, __HIP_MEMORY_SCOPE_AGENT) < rtgt)
            __builtin_amdgcn_s_sleep(2);
        __threadfence();                             // acquire: skey visible
    }
    __syncthreads();

    for (int j = tid; j < 2048; j += NTHR) sm.c.avail[j] = 1;
    const u64 lmask = (lane == 0) ? 0ull : ((~0ull) >> (64 - lane));
    const long long gbase = (long long)g * T;

    for (int e = 0; e < NEXP; ++e) {
        const long long kb = (long long)(e * G + g) * T;
        u64 k[4];
#pragma unroll
        for (int j = 0; j < 4; ++j) k[j] = skey[kb + tid + j * NTHR];
        __syncthreads();                             // B_top: prior updates visible
        u32 idx[4]; int f[4]; u64 m[4];
#pragma unroll
        for (int j = 0; j < 4; ++j) {
            idx[j] = ~(u32)k[j];
            f[j] = sm.c.avail[idx[j]];
            m[j] = __ballot(f[j]);
            if (lane == 0) sm.c.cnt[wv + 8 * j] = __popcll(m[j]);
        }
        __syncthreads();                             // B1
        int vi = (lane < 32) ? sm.c.cnt[lane] : 0;
#pragma unroll
        for (int o = 1; o < 32; o <<= 1) { const int t2 = __shfl_up(vi, o, 64); if (lane >= o) vi += t2; }
        const int S = __shfl(vi, 31, 64);
        bool sel[4]; int pre[4];
#pragma unroll
        for (int j = 0; j < 4; ++j) {
            const int seg = wv + 8 * j;
            const int off = seg ? __shfl(vi, seg - 1, 64) : 0;
            pre[j] = off + __popcll(m[j] & lmask);
            sel[j] = f[j] && (pre[j] < cap);
            if (sel[j]) sm.c.cbuf[e * cap + pre[j]] = ((k[j] >> 32) << 32) | (u64)idx[j];
        }
        if (S < cap) {
            // zero-gate fill: smallest-index unavailable tokens (val = 0)
            int u[4]; u64 n[4];
#pragma unroll
            for (int j = 0; j < 4; ++j) {
                u[j] = 1 - sm.c.avail[tid + j * NTHR];
                n[j] = __ballot(u[j]);
                if (lane == 0) sm.c.cnt2[wv + 8 * j] = __popcll(n[j]);
            }
            __syncthreads();                         // B2: cnt2 visible; u-reads done
            int vj = (lane < 32) ? sm.c.cnt2[lane] : 0;
#pragma unroll
            for (int o = 1; o < 32; o <<= 1) { const int t2 = __shfl_up(vj, o, 64); if (lane >= o) vj += t2; }
            const int nfill = cap - S;
#pragma unroll
            for (int j = 0; j < 4; ++j) {
                const int seg = wv + 8 * j;
                const int qoff = seg ? __shfl(vj, seg - 1, 64) : 0;
                const int qj = qoff + __popcll(n[j] & lmask);
                if (u[j] && qj < nfill) sm.c.cbuf[e * cap + S + qj] = (u64)(u32)(tid + j * NTHR);
            }
        }
#pragma unroll
        for (int j = 0; j < 4; ++j) if (sel[j]) sm.c.avail[idx[j]] = 0;
    }
    __syncthreads();                                 // cbuf complete

    // z_loss + tail scalars (group-0 block): needs ALL probs blocks done
    if (g == 0) {
        if (tid == 0) {
            const int ptgt = NPB / 4;
#pragma unroll
            for (int gg = 0; gg < 4; ++gg)
                while (__hip_atomic_load(&flags[gg], __ATOMIC_RELAXED, __HIP_MEMORY_SCOPE_AGENT) < ptgt)
                    __builtin_amdgcn_s_sleep(2);
            __threadfence();
        }
        __syncthreads();
        if (tid < 64) {
            double s = 0.0;
            for (int i = tid; i < NPB; i += 64) s += zpart[i];
#pragma unroll
            for (int o = 32; o; o >>= 1) s += __shfl_xor(s, o, 64);
            if (tid == 0) {
                float* sc = out + 2 * GT * (long long)NEXP * cap;
                // zero any tail floats not covered by float4 fill
                for (long long j = nout4 * 4; j < (long long)out_size - 3; ++j) out[j] = 0.f;
                sc[0] = 0.0f;
                sc[1] = (float)(s / (double)GT);
                sc[2] = 0.0f;
            }
        }
    }

    // wait for fill completion, then scatter compact entries
    if (tid == 0) {
        while (__hip_atomic_load(&flags[8], __ATOMIC_RELAXED, __HIP_MEMORY_SCOPE_AGENT) < NFL)
            __builtin_amdgcn_s_sleep(2);
        __threadfence();                             // acquire: zeros landed
    }
    __syncthreads();

    float* dispatch = out;
    float* combine  = out + GT * (long long)NEXP * cap;
#pragma unroll
    for (int e = 0; e < NEXP; ++e) {
        for (int c = tid; c < cap; c += NTHR) {
            const u64 en = sm.c.cbuf[e * cap + c];
            const u32 idx = (u32)en;
            const float val = __uint_as_float((u32)(en >> 32));
            const long long o_ = ((gbase + idx) * NEXP + e) * (long long)cap + c;
            dispatch[o_] = 1.0f;
            combine[o_]  = val;
        }
    }
}

extern "C" void kernel_launch(void* const* d_in, const int* in_sizes, int n_in,
                              void* d_out, int out_size, void* d_ws, size_t ws_size,
                              hipStream_t stream) {
    (void)n_in; (void)ws_size;
    const float* x    = (const float*)d_in[0];
    const float* w    = (const float*)d_in[1];
    const float* bias = (const float*)d_in[2];

    const int E = in_sizes[2];                        // 8
    const int D = in_sizes[1] / E;                    // 1024
    const long long GT = (long long)in_sizes[0] / D;  // 8192
    const int T = 2048;
    const int G = (int)(GT / T);                      // 4
    const int cap = (int)(((long long)out_size - 3) / (2 * GT * E));
    const long long nout4 = ((long long)out_size - 3) >> 2;

    int*    flags  = (int*)d_ws;                                   // [0,64)
    double* zpart  = (double*)((char*)d_ws + 4096);                // NPB*8 B
    float*  probsT = (float*)((char*)d_ws + 16384);                // E*GT*4
    u64*    skey   = (u64*)((char*)d_ws + 16384 + (size_t)E * GT * sizeof(float));

    hipMemsetAsync(flags, 0, 64, stream);            // flag counters -> 0 each call

    moe_fat_kernel<<<NPB + NFL + NRK + G, NTHR, 0, stream>>>(
        x, w, bias, (float*)d_out, probsT, skey, zpart, flags,
        nout4, out_size, GT, T, G, cap);
}

// Round 9
// 108.223 us; speedup vs baseline: 1.7729x; 1.7729x over previous
//
#include <hip/hip_runtime.h>

#define NEXP 8
#define NPB 1024        // probs blocks (8 tokens each)
#define NRK 256         // rank blocks (32 pairs x 8 slices)
#define NFL 2048        // fill blocks
#define NTHR 512

typedef unsigned long long u64;
typedef unsigned int u32;

#define LOAD_AGT(p)     __hip_atomic_load((p), __ATOMIC_RELAXED, __HIP_MEMORY_SCOPE_AGENT)
#define STORE_AGT(p,v)  __hip_atomic_store((p), (v), __ATOMIC_RELAXED, __HIP_MEMORY_SCOPE_AGENT)
#define ADD_AGT(p,v)    __hip_atomic_fetch_add((p), (v), __ATOMIC_RELAXED, __HIP_MEMORY_SCOPE_AGENT)

union __align__(16) Smem {
    struct { float wl[NEXP * 1024]; double zred[8]; } a;      // probs
    struct { u64 keys[2048]; int part[NTHR]; } b;             // rank
    struct { int avail[2048]; int cnt[32]; int cnt2[32]; } c; // assign
};

// flags: [0..G) pflag (target NPB/G), [G..2G) rkflag (target NRK/G)
__global__ __launch_bounds__(NTHR) void moe_main_kernel(
    const float* __restrict__ x,      // [GT, 1024]
    const float* __restrict__ w,      // [8, 1024]
    const float* __restrict__ bias,   // [8]
    float* __restrict__ out,
    float* probsT,                    // [E][GT]   (LLC-coherent channel)
    u64* skey,                        // [E*G][T]  (LLC-coherent channel)
    double* zpart,                    // [NPB]     (LLC-coherent channel)
    u64* cbufg,                       // [G][E][cap] compact results (read by k2)
    double* zsc,                      // [1] z accumulator (read by k2)
    int* flags,                       // zeroed by memset node
    long long nout4, long long GT, int T, int G, int cap)
{
    __shared__ Smem sm;
    const int b = blockIdx.x;
    const int tid = threadIdx.x;
    const int lane = tid & 63;
    const int wv = tid >> 6;

    if (b < NPB) {
        // ================= probs: 8 tokens, one per wave; NO fences =========
        for (int i = tid; i < NEXP * 1024 / 4; i += NTHR)
            reinterpret_cast<float4*>(sm.a.wl)[i] = reinterpret_cast<const float4*>(w)[i];
        __syncthreads();

        const long long t = (long long)b * 8 + wv;
        const float* xr = x + t * 1024;
        float acc[NEXP];
#pragma unroll
        for (int e = 0; e < NEXP; ++e) acc[e] = 0.f;
#pragma unroll
        for (int c = 0; c < 4; ++c) {
            const int d = c * 256 + lane * 4;
            const float4 xv = *reinterpret_cast<const float4*>(xr + d);
#pragma unroll
            for (int e = 0; e < NEXP; ++e) {
                const float4 wv4 = *reinterpret_cast<const float4*>(sm.a.wl + e * 1024 + d);
                acc[e] = fmaf(xv.x, wv4.x, acc[e]);
                acc[e] = fmaf(xv.y, wv4.y, acc[e]);
                acc[e] = fmaf(xv.z, wv4.z, acc[e]);
                acc[e] = fmaf(xv.w, wv4.w, acc[e]);
            }
        }
#pragma unroll
        for (int e = 0; e < NEXP; ++e) {
#pragma unroll
            for (int off = 32; off; off >>= 1) acc[e] += __shfl_xor(acc[e], off, 64);
        }
        if (lane == 0) {
            double l[NEXP]; double mx = -1e300;
#pragma unroll
            for (int e = 0; e < NEXP; ++e) { l[e] = (double)acc[e] + (double)bias[e]; mx = fmax(mx, l[e]); }
            double ex[NEXP]; double s = 0.0;
#pragma unroll
            for (int e = 0; e < NEXP; ++e) { ex[e] = exp(l[e] - mx); s += ex[e]; }
            const double inv = 1.0 / s;
#pragma unroll
            for (int e = 0; e < NEXP; ++e)
                STORE_AGT(&probsT[(long long)e * GT + t], (float)(ex[e] * inv));
            const double lse = mx + log(s);
            sm.a.zred[wv] = lse * lse;
        }
        __syncthreads();   // drains all waves' sc1 stores (vmcnt 0 before barrier)
        if (tid == 0) {
            double s = 0.0;
#pragma unroll
            for (int i = 0; i < 8; ++i) s += sm.a.zred[i];
            STORE_AGT(&zpart[b], s);
            asm volatile("s_waitcnt vmcnt(0)" ::: "memory");   // zpart landed
            ADD_AGT(&flags[b / (NPB / 4)], 1);                 // pflag[g]
        }
        return;
    }

    if (b < NPB + NRK) {
        // ================= rank: pair = e*G+g, slice of 256 tokens ==========
        const int b2 = b - NPB;
        const int pair = b2 >> 3;
        const int sub  = b2 & 7;
        const int e = pair / G;
        const int g = pair - e * G;
        const int ptgt = NPB / 4;
        if (tid == 0) {
            while (LOAD_AGT(&flags[g]) < ptgt) __builtin_amdgcn_s_sleep(2);
        }
        __syncthreads();

        float* p = probsT + (long long)e * GT + (long long)g * T;
        for (int j = tid; j < 2048; j += NTHR)
            sm.b.keys[j] = ((u64)__float_as_uint(LOAD_AGT(&p[j])) << 32) | (u32)(~(u32)j);
        __syncthreads();
        const int slot = tid & 255;
        const int q = tid >> 8;            // compare-range half 0..1
        const u64 kt = sm.b.keys[sub * 256 + slot];
        const ulonglong2* k2p = reinterpret_cast<const ulonglong2*>(sm.b.keys) + q * 512;
        int r = 0;
#pragma unroll 8
        for (int j = 0; j < 512; ++j) {
            const ulonglong2 v = k2p[j];
            r += (v.x > kt); r += (v.y > kt);
        }
        sm.b.part[tid] = r;
        __syncthreads();
        if (tid < 256) {
            const int rank = sm.b.part[tid] + sm.b.part[tid + 256];
            STORE_AGT(&skey[(long long)pair * T + rank], sm.b.keys[sub * 256 + tid]);
        }
        __syncthreads();   // drains skey sc1 stores
        if (tid == 0) ADD_AGT(&flags[4 + g], 1);
        return;
    }

    if (b < NPB + NRK + G) {
        // ================= assign for group g; results -> cbufg (plain) =====
        const int g = b - NPB - NRK;
        const int rtgt = NRK / 4;
        if (tid == 0) {
            while (LOAD_AGT(&flags[4 + g]) < rtgt) __builtin_amdgcn_s_sleep(2);
            if (g == 0) {
                const int ptgt = NPB / 4;
                for (int gg = 0; gg < 4; ++gg)
                    while (LOAD_AGT(&flags[gg]) < ptgt) __builtin_amdgcn_s_sleep(2);
            }
        }
        __syncthreads();

        for (int j = tid; j < 2048; j += NTHR) sm.c.avail[j] = 1;
        const u64 lmask = (lane == 0) ? 0ull : ((~0ull) >> (64 - lane));
        u64* cb = cbufg + (long long)g * NEXP * cap;

        for (int e = 0; e < NEXP; ++e) {
            const long long kb = (long long)(e * G + g) * T;
            u64 k[4];
#pragma unroll
            for (int j = 0; j < 4; ++j) k[j] = LOAD_AGT(&skey[kb + tid + j * NTHR]);
            __syncthreads();                         // B_top: prior avail updates visible
            u32 idx[4]; int f[4]; u64 m[4];
#pragma unroll
            for (int j = 0; j < 4; ++j) {
                idx[j] = ~(u32)k[j];
                f[j] = sm.c.avail[idx[j]];
                m[j] = __ballot(f[j]);
                if (lane == 0) sm.c.cnt[wv + 8 * j] = __popcll(m[j]);
            }
            __syncthreads();                         // B1
            int vi = (lane < 32) ? sm.c.cnt[lane] : 0;
#pragma unroll
            for (int o = 1; o < 32; o <<= 1) { const int t2 = __shfl_up(vi, o, 64); if (lane >= o) vi += t2; }
            const int S = __shfl(vi, 31, 64);
            bool sel[4];
#pragma unroll
            for (int j = 0; j < 4; ++j) {
                const int seg = wv + 8 * j;
                const int off = seg ? __shfl(vi, seg - 1, 64) : 0;
                const int pre = off + __popcll(m[j] & lmask);
                sel[j] = f[j] && (pre < cap);
                if (sel[j]) cb[e * cap + pre] = ((k[j] >> 32) << 32) | (u64)idx[j];
            }
            if (S < cap) {
                // zero-gate fill: smallest-index unavailable tokens (val = 0)
                int u[4]; u64 n[4];
#pragma unroll
                for (int j = 0; j < 4; ++j) {
                    u[j] = 1 - sm.c.avail[tid + j * NTHR];
                    n[j] = __ballot(u[j]);
                    if (lane == 0) sm.c.cnt2[wv + 8 * j] = __popcll(n[j]);
                }
                __syncthreads();                     // B2: cnt2 visible; u-reads done
                int vj = (lane < 32) ? sm.c.cnt2[lane] : 0;
#pragma unroll
                for (int o = 1; o < 32; o <<= 1) { const int t2 = __shfl_up(vj, o, 64); if (lane >= o) vj += t2; }
                const int nfill = cap - S;
#pragma unroll
                for (int j = 0; j < 4; ++j) {
                    const int seg = wv + 8 * j;
                    const int qoff = seg ? __shfl(vj, seg - 1, 64) : 0;
                    const int qj = qoff + __popcll(n[j] & lmask);
                    if (u[j] && qj < nfill) cb[e * cap + S + qj] = (u64)(u32)(tid + j * NTHR);
                }
            }
#pragma unroll
            for (int j = 0; j < 4; ++j) if (sel[j]) sm.c.avail[idx[j]] = 0;
        }

        // z_loss partial sum -> zsc (plain store; k2 reads after kernel boundary)
        if (g == 0) {
            __syncthreads();
            if (tid < 64) {
                double s = 0.0;
                for (int i = tid; i < NPB; i += 64) s += LOAD_AGT(&zpart[i]);
#pragma unroll
                for (int o = 32; o; o >>= 1) s += __shfl_xor(s, o, 64);
                if (tid == 0) zsc[0] = s;
            }
        }
        return;
    }

    // ================= fill: pure zero streaming, NO flags, NO fences =======
    const int fb = b - (NPB + NRK + 4);
    const long long stride = (long long)NFL * NTHR;
    const float4 z = make_float4(0.f, 0.f, 0.f, 0.f);
    for (long long k = (long long)fb * NTHR + tid; k < nout4; k += stride)
        reinterpret_cast<float4*>(out)[k] = z;
}

// ---------------- kernel 2: scatter compact results over k1's zeros ----------
__global__ __launch_bounds__(NTHR) void scatter_kernel(
    const u64* __restrict__ cbufg,   // [G][E][cap]
    const double* __restrict__ zsc,
    float* __restrict__ out,
    long long nout4, int out_size,
    int T, int G, int cap, long long GT)
{
    const int g = blockIdx.x;
    const int tid = threadIdx.x;
    float* dispatch = out;
    float* combine  = out + GT * (long long)NEXP * cap;
    const long long gbase = (long long)g * T;
    const u64* cb = cbufg + (long long)g * NEXP * cap;

#pragma unroll
    for (int e = 0; e < NEXP; ++e) {
        for (int c = tid; c < cap; c += NTHR) {
            const u64 en = cb[e * cap + c];
            const u32 idx = (u32)en;
            const float val = __uint_as_float((u32)(en >> 32));
            const long long o_ = ((gbase + idx) * NEXP + e) * (long long)cap + c;
            dispatch[o_] = 1.0f;
            combine[o_]  = val;
        }
    }
    if (g == 0 && tid == 0) {
        float* sc = out + 2 * GT * (long long)NEXP * cap;
        for (long long j = nout4 * 4; j < (long long)out_size - 3; ++j) out[j] = 0.f;
        sc[0] = 0.0f;
        sc[1] = (float)(zsc[0] / (double)GT);
        sc[2] = 0.0f;
    }
}

extern "C" void kernel_launch(void* const* d_in, const int* in_sizes, int n_in,
                              void* d_out, int out_size, void* d_ws, size_t ws_size,
                              hipStream_t stream) {
    (void)n_in; (void)ws_size;
    const float* x    = (const float*)d_in[0];
    const float* w    = (const float*)d_in[1];
    const float* bias = (const float*)d_in[2];

    const int E = in_sizes[2];                        // 8
    const int D = in_sizes[1] / E;                    // 1024
    const long long GT = (long long)in_sizes[0] / D;  // 8192
    const int T = 2048;
    const int G = (int)(GT / T);                      // 4
    const int cap = (int)(((long long)out_size - 3) / (2 * GT * E));
    const long long nout4 = ((long long)out_size - 3) >> 2;

    int*    flags  = (int*)d_ws;                                   // [0,64)
    double* zsc    = (double*)((char*)d_ws + 256);                 // 8 B
    double* zpart  = (double*)((char*)d_ws + 4096);                // NPB*8
    float*  probsT = (float*)((char*)d_ws + 16384);                // E*GT*4
    u64*    skey   = (u64*)((char*)d_ws + 16384 + (size_t)E * GT * sizeof(float));
    u64*    cbufg  = (u64*)((char*)d_ws + 16384 + (size_t)E * GT * sizeof(float)
                                        + (size_t)E * G * T * sizeof(u64));

    hipMemsetAsync(flags, 0, 64, stream);             // flag counters -> 0 each call

    moe_main_kernel<<<NPB + NRK + G + NFL, NTHR, 0, stream>>>(
        x, w, bias, (float*)d_out, probsT, skey, zpart, cbufg, zsc, flags,
        nout4, GT, T, G, cap);

    scatter_kernel<<<G, NTHR, 0, stream>>>(
        cbufg, zsc, (float*)d_out, nout4, out_size, T, G, cap, GT);
}

// Round 10
// 78.003 us; speedup vs baseline: 2.4598x; 1.3874x over previous
//
#include <hip/hip_runtime.h>

#define NEXP 8
#define NPB 1024        // probs role-blocks (8 tokens each)
#define NFB 2048        // fill role-blocks
#define NRK 256         // rank blocks (32 pairs x 8 slices)
#define NTHR 512

typedef unsigned long long u64;
typedef unsigned int u32;

// ---------------- kernel 1: interleaved probs + zero-fill (fence-free) -------
// role by blockIdx%3: 0 -> probs (b/3), 1,2 -> fill ((b/3)*2 + r-1).
__global__ __launch_bounds__(NTHR) void probs_fill_kernel(
    const float* __restrict__ x,      // [GT, 1024]
    const float* __restrict__ w,      // [8, 1024]
    const float* __restrict__ bias,   // [8]
    float* __restrict__ probsT,       // [E][GT]
    double* __restrict__ zpart,       // [NPB]
    int* __restrict__ flags,          // zeroed here; consumed by kernel 2
    float* __restrict__ out,
    long long nout4, long long GT)
{
    const int b = blockIdx.x;
    if (b == 0 && threadIdx.x < 16) flags[threadIdx.x] = 0;

    const int r3 = b % 3;
    if (r3 != 0) {
        // ---- fill path: pure zero streaming, no LDS use, no flags ----
        const int fi = (b / 3) * 2 + (r3 - 1);
        const long long stride = (long long)NFB * NTHR;
        const float4 z = make_float4(0.f, 0.f, 0.f, 0.f);
        for (long long k = (long long)fi * NTHR + threadIdx.x; k < nout4; k += stride)
            reinterpret_cast<float4*>(out)[k] = z;
        return;
    }

    // ---- probs path: 8 tokens, one per wave ----
    __shared__ float wl[NEXP * 1024];
    __shared__ double zred[8];
    const int pb = b / 3;
    const int tid = threadIdx.x;
    const int lane = tid & 63;
    const int wave = tid >> 6;

    for (int i = tid; i < NEXP * 1024 / 4; i += NTHR)
        reinterpret_cast<float4*>(wl)[i] = reinterpret_cast<const float4*>(w)[i];
    __syncthreads();

    const long long t = (long long)pb * 8 + wave;
    const float* xr = x + t * 1024;
    float acc[NEXP];
#pragma unroll
    for (int e = 0; e < NEXP; ++e) acc[e] = 0.f;
#pragma unroll
    for (int c = 0; c < 4; ++c) {
        const int d = c * 256 + lane * 4;
        const float4 xv = *reinterpret_cast<const float4*>(xr + d);
#pragma unroll
        for (int e = 0; e < NEXP; ++e) {
            const float4 wv = *reinterpret_cast<const float4*>(wl + e * 1024 + d);
            acc[e] = fmaf(xv.x, wv.x, acc[e]);
            acc[e] = fmaf(xv.y, wv.y, acc[e]);
            acc[e] = fmaf(xv.z, wv.z, acc[e]);
            acc[e] = fmaf(xv.w, wv.w, acc[e]);
        }
    }
#pragma unroll
    for (int e = 0; e < NEXP; ++e) {
#pragma unroll
        for (int off = 32; off; off >>= 1) acc[e] += __shfl_xor(acc[e], off, 64);
    }

    if (lane == 0) {
        double l[NEXP]; double mx = -1e300;
#pragma unroll
        for (int e = 0; e < NEXP; ++e) { l[e] = (double)acc[e] + (double)bias[e]; mx = fmax(mx, l[e]); }
        double ex[NEXP]; double s = 0.0;
#pragma unroll
        for (int e = 0; e < NEXP; ++e) { ex[e] = exp(l[e] - mx); s += ex[e]; }
        const double inv = 1.0 / s;
#pragma unroll
        for (int e = 0; e < NEXP; ++e) probsT[(long long)e * GT + t] = (float)(ex[e] * inv);
        const double lse = mx + log(s);
        zred[wave] = lse * lse;
    }
    __syncthreads();
    if (tid == 0) {
        double s = 0.0;
#pragma unroll
        for (int i = 0; i < 8; ++i) s += zred[i];
        zpart[pb] = s;
    }
}

// ------- kernel 2: rank [0,256) -> assign [256,260), 512 threads -------------
union __align__(16) Smem2 {
    struct { u64 keys[2048]; int part[NTHR]; } b;             // rank: 18 KB
    struct { int avail[2048]; int cnt[32]; int cnt2[32]; } c; // assign
};

__global__ __launch_bounds__(NTHR) void rank_assign_kernel(
    const float* __restrict__ probsT,  // [E][GT]
    u64* __restrict__ skey,            // [E*G][T]
    int* __restrict__ flags,           // zeroed by kernel 1
    const double* __restrict__ zpart,
    float* __restrict__ out,
    long long nout4, int out_size,
    int T, int G, int cap, long long GT)
{
    __shared__ Smem2 sm;
    const int b = blockIdx.x;
    const int tid = threadIdx.x;
    const int lane = tid & 63;
    const int wv = tid >> 6;

    if (b < NRK) {
        // ---- ranksort slice: pair = e*G+g, slice sub of 256 tokens ----
        const int pair = b >> 3;
        const int sub  = b & 7;
        const int e = pair / G;
        const int g = pair - e * G;
        const float* p = probsT + (long long)e * GT + (long long)g * T;
        {   // vectorized key staging: one float4 per thread
            const float4 pv = reinterpret_cast<const float4*>(p)[tid];
            const int j = tid * 4;
            sm.b.keys[j + 0] = ((u64)__float_as_uint(pv.x) << 32) | (u32)(~(u32)(j + 0));
            sm.b.keys[j + 1] = ((u64)__float_as_uint(pv.y) << 32) | (u32)(~(u32)(j + 1));
            sm.b.keys[j + 2] = ((u64)__float_as_uint(pv.z) << 32) | (u32)(~(u32)(j + 2));
            sm.b.keys[j + 3] = ((u64)__float_as_uint(pv.w) << 32) | (u32)(~(u32)(j + 3));
        }
        __syncthreads();
        const int slot = tid & 255;
        const int q = tid >> 8;            // compare-range half 0..1
        const u64 kt = sm.b.keys[sub * 256 + slot];
        const ulonglong2* k2p = reinterpret_cast<const ulonglong2*>(sm.b.keys) + q * 512;
        int r = 0;
#pragma unroll 8
        for (int j = 0; j < 512; ++j) {
            const ulonglong2 v = k2p[j];
            r += (v.x > kt); r += (v.y > kt);
        }
        sm.b.part[tid] = r;
        __syncthreads();
        if (tid < 256) {
            const int rank = sm.b.part[tid] + sm.b.part[tid + 256];
            skey[(long long)pair * T + rank] = sm.b.keys[sub * 256 + tid];
        }
        __syncthreads();   // skey stores drained before flag release
        if (tid == 0) { __threadfence(); atomicAdd(&flags[g], 1); }
        return;
    }

    // ---- assign block for group g: wait for its 64 rank producers ----
    const int g = b - NRK;
    if (tid == 0) {
        while (__hip_atomic_load(&flags[g], __ATOMIC_RELAXED, __HIP_MEMORY_SCOPE_AGENT) < NRK / 4)
            __builtin_amdgcn_s_sleep(2);
        __threadfence();   // acquire: skey visible
    }
    __syncthreads();

    for (int j = tid; j < 2048; j += NTHR) sm.c.avail[j] = 1;
    const u64 lmask = (lane == 0) ? 0ull : ((~0ull) >> (64 - lane));
    const long long gbase = (long long)g * T;
    float* dispatch = out;
    float* combine  = out + GT * (long long)NEXP * cap;

    for (int e = 0; e < NEXP; ++e) {
        const long long kb = (long long)(e * G + g) * T;
        u64 k[4];
#pragma unroll
        for (int j = 0; j < 4; ++j) k[j] = skey[kb + tid + j * NTHR];
        __syncthreads();                         // B_top: prior avail updates visible
        u32 idx[4]; int f[4]; u64 m[4];
#pragma unroll
        for (int j = 0; j < 4; ++j) {
            idx[j] = ~(u32)k[j];
            f[j] = sm.c.avail[idx[j]];
            m[j] = __ballot(f[j]);
            if (lane == 0) sm.c.cnt[wv + 8 * j] = __popcll(m[j]);
        }
        __syncthreads();                         // B1
        int vi = (lane < 32) ? sm.c.cnt[lane] : 0;
#pragma unroll
        for (int o = 1; o < 32; o <<= 1) { const int t2 = __shfl_up(vi, o, 64); if (lane >= o) vi += t2; }
        const int S = __shfl(vi, 31, 64);
        bool sel[4];
#pragma unroll
        for (int j = 0; j < 4; ++j) {
            const int seg = wv + 8 * j;
            const int off = seg ? __shfl(vi, seg - 1, 64) : 0;
            const int pre = off + __popcll(m[j] & lmask);
            sel[j] = f[j] && (pre < cap);
            if (sel[j]) {
                const long long o_ = ((gbase + idx[j]) * NEXP + e) * (long long)cap + pre;
                dispatch[o_] = 1.0f;
                combine[o_]  = __uint_as_float((u32)(k[j] >> 32));
            }
        }
        if (S < cap) {
            // zero-gate fill: smallest-index unavailable tokens (combine stays 0)
            int u[4]; u64 n[4];
#pragma unroll
            for (int j = 0; j < 4; ++j) {
                u[j] = 1 - sm.c.avail[tid + j * NTHR];
                n[j] = __ballot(u[j]);
                if (lane == 0) sm.c.cnt2[wv + 8 * j] = __popcll(n[j]);
            }
            __syncthreads();                     // B2: cnt2 visible; u-reads done
            int vj = (lane < 32) ? sm.c.cnt2[lane] : 0;
#pragma unroll
            for (int o = 1; o < 32; o <<= 1) { const int t2 = __shfl_up(vj, o, 64); if (lane >= o) vj += t2; }
            const int nfill = cap - S;
#pragma unroll
            for (int j = 0; j < 4; ++j) {
                const int seg = wv + 8 * j;
                const int qoff = seg ? __shfl(vj, seg - 1, 64) : 0;
                const int qj = qoff + __popcll(n[j] & lmask);
                if (u[j] && qj < nfill) {
                    const long long o_ = ((gbase + tid + j * NTHR) * NEXP + e) * (long long)cap + S + qj;
                    dispatch[o_] = 1.0f;
                }
            }
        }
#pragma unroll
        for (int j = 0; j < 4; ++j) if (sel[j]) sm.c.avail[idx[j]] = 0;
    }

    // z_loss + tail scalars (group-0 assign block)
    if (g == 0) {
        __syncthreads();
        if (tid < 64) {
            double s = 0.0;
            for (int i = tid; i < NPB; i += 64) s += zpart[i];
#pragma unroll
            for (int o = 32; o; o >>= 1) s += __shfl_xor(s, o, 64);
            if (tid == 0) {
                float* sc = out + 2 * GT * (long long)NEXP * cap;
                for (long long j = nout4 * 4; j < (long long)out_size - 3; ++j) out[j] = 0.f;
                sc[0] = 0.0f;
                sc[1] = (float)(s / (double)GT);
                sc[2] = 0.0f;
            }
        }
    }
}

extern "C" void kernel_launch(void* const* d_in, const int* in_sizes, int n_in,
                              void* d_out, int out_size, void* d_ws, size_t ws_size,
                              hipStream_t stream) {
    (void)n_in; (void)ws_size;
    const float* x    = (const float*)d_in[0];
    const float* w    = (const float*)d_in[1];
    const float* bias = (const float*)d_in[2];

    const int E = in_sizes[2];                        // 8
    const int D = in_sizes[1] / E;                    // 1024
    const long long GT = (long long)in_sizes[0] / D;  // 8192
    const int T = 2048;
    const int G = (int)(GT / T);                      // 4
    const int cap = (int)(((long long)out_size - 3) / (2 * GT * E));
    const long long nout4 = ((long long)out_size - 3) >> 2;

    int*    flags  = (int*)d_ws;                                   // [0,64)
    double* zpart  = (double*)((char*)d_ws + 4096);                // NPB*8 B
    float*  probsT = (float*)((char*)d_ws + 16384);                // E*GT*4
    u64*    skey   = (u64*)((char*)d_ws + 16384 + (size_t)E * GT * sizeof(float));

    probs_fill_kernel<<<NPB + NFB, NTHR, 0, stream>>>(
        x, w, bias, probsT, zpart, flags, (float*)d_out, nout4, GT);

    rank_assign_kernel<<<NRK + G, NTHR, 0, stream>>>(
        probsT, skey, flags, zpart, (float*)d_out, nout4, out_size, T, G, cap, GT);
}